// Round 9
// baseline (862.553 us; speedup 1.0000x reference)
//
#include <hip/hip_runtime.h>

#define B_ 8
#define C_ 64
#define N_ 4096
#define O_ 64
#define E_ 128
#define K_ 20
#define EPS_ 1e-5f

typedef float v2f __attribute__((ext_vector_type(2)));
typedef __attribute__((ext_vector_type(4)))  int  i32x4;
typedef __attribute__((ext_vector_type(16))) int  i32x16;
typedef __attribute__((ext_vector_type(16))) char c16;

// ---- workspace layout (float offsets) ----
#define WS_SQ    0                          // (B,N) |p_quant|^2 fp32
#define WS_Y     32768                      // (B,N,O)
#define WS_Z     (WS_Y + B_*N_*O_)          // (B,N,O)
#define WS_M     (WS_Z + B_*N_*O_)          // (B,O,N)
#define WS_GAMMA (WS_M + B_*N_*O_)
#define WS_BETA  (WS_GAMMA + 512)
#define WS_SCALE (WS_BETA + 512)
#define WS_SHIFT (WS_SCALE + 512)
#define WS_END_F (WS_SHIFT + 512)
#define WS_I8B   (WS_END_F * 4)             // BYTE offset of i8 limb blobs
// blob per (b,tile): 16384 B = 3 planes x (64 rows x 80 B) + 1024 pad
// plane p, row r, channel c: byte p*5120 + r*80 + c

// ===================== k0: domain MLPs -> gamma/beta =====================
__global__ __launch_bounds__(256) void k0_mlp(const float* __restrict__ emb,
    const float* __restrict__ gw1, const float* __restrict__ gb1,
    const float* __restrict__ gw2, const float* __restrict__ gb2,
    const float* __restrict__ bw1, const float* __restrict__ bb1,
    const float* __restrict__ bw2, const float* __restrict__ bb2,
    float* __restrict__ ws)
{
  __shared__ float s_emb[B_][E_];
  __shared__ float s_h[2][B_][E_];
  int t = threadIdx.x;
  for (int i = t; i < B_*E_; i += 256) s_emb[i >> 7][i & 127] = emb[i];
  __syncthreads();
  {
    int net = t >> 7, e = t & 127;
    const float* w1 = net ? bw1 : gw1;
    const float* b1 = net ? bb1 : gb1;
    float acc[B_];
#pragma unroll
    for (int b = 0; b < B_; ++b) acc[b] = 0.f;
    const float* row = w1 + e * E_;
    for (int j = 0; j < E_; j += 4) {
      float4 w = *(const float4*)(row + j);
#pragma unroll
      for (int b = 0; b < B_; ++b)
        acc[b] += s_emb[b][j]*w.x + s_emb[b][j+1]*w.y + s_emb[b][j+2]*w.z + s_emb[b][j+3]*w.w;
    }
    float bias = b1[e];
#pragma unroll
    for (int b = 0; b < B_; ++b) s_h[net][b][e] = fmaxf(acc[b] + bias, 0.f);
  }
  __syncthreads();
  for (int r = 0; r < 4; ++r) {
    int idx = t + 256 * r;
    int net = idx >> 9, b = (idx >> 6) & 7, o = idx & 63;
    const float* w2 = net ? bw2 : gw2;
    const float* b2 = net ? bb2 : gb2;
    const float* row = w2 + o * E_;
    float acc = 0.f;
    for (int e = 0; e < E_; e += 4) {
      float4 w = *(const float4*)(row + e);
      acc += s_h[net][b][e]*w.x + s_h[net][b][e+1]*w.y + s_h[net][b][e+2]*w.z + s_h[net][b][e+3]*w.w;
    }
    acc += b2[o];
    if (net == 0) ws[WS_GAMMA + b*O_ + o] = 1.f + acc;
    else          ws[WS_BETA  + b*O_ + o] = acc;
  }
}

// ===================== k1a: quantize x -> 3 i8 limb planes + exact |p|^2 ====
__global__ __launch_bounds__(256) void k1a_split(const float* __restrict__ x, float* __restrict__ ws)
{
  __shared__ double sqp[4][64];
  int b = blockIdx.y, T = blockIdx.x, n0 = T * 64;
  int t = threadIdx.x;
  int r = t & 63, qc = t >> 6;
  char* blob = (char*)ws + WS_I8B + (size_t)(b * 64 + T) * 16384;
  c16 v0, v1, v2;
  double sq = 0.0;
#pragma unroll
  for (int e = 0; e < 16; ++e) {
    int c = qc * 16 + e;
    float v = x[((size_t)(b * 64 + c)) * 4096 + n0 + r];
    int X = __float2int_rn(v * 1048576.0f);          // 2^20
    sq += (double)X * (double)X;
    int L0 = ((X + 128) & 255) - 128;
    int X1 = (X - L0) >> 8;
    int L1 = ((X1 + 128) & 255) - 128;
    int L2 = (X1 - L1) >> 8;
    v0[e] = (char)L0; v1[e] = (char)L1; v2[e] = (char)L2;
  }
  *(c16*)(blob + 0*5120 + r*80 + qc*16) = v0;
  *(c16*)(blob + 1*5120 + r*80 + qc*16) = v1;
  *(c16*)(blob + 2*5120 + r*80 + qc*16) = v2;
  sqp[qc][r] = sq;
  __syncthreads();
  if (t < 64)
    ws[WS_SQ + b * N_ + n0 + t] =
      (float)((sqp[0][t] + sqp[1][t] + sqp[2][t] + sqp[3][t]) * (1.0 / 1099511627776.0)); // 2^-40
}

// ===================== k1b: Y = wa.p, Z = wb.p (coalesced writes) ===========
__global__ __launch_bounds__(256) void k1b_yz(const float* __restrict__ x,
                                              const float* __restrict__ cw_, float* __restrict__ ws)
{
  extern __shared__ char l1b[];
  float* P   = (float*)l1b;              // [64][65]
  float* waT = (float*)(l1b + 16640);    // [64][64]
  float* wbT = (float*)(l1b + 33024);    // [64][64]
  float* YT  = (float*)l1b;              // [64][65] overlay
  float* ZT  = (float*)(l1b + 16900);    // [64][65] overlay
  int b = blockIdx.y, n0 = blockIdx.x * 64;
  int t = threadIdx.x;
  {
    int o = t & 63, cb = t >> 6;
#pragma unroll
    for (int k = 0; k < 16; ++k) {
      int c = cb + 4 * k;
      float w1v = cw_[o * 128 + c];
      float w2v = cw_[o * 128 + 64 + c];
      waT[c * 64 + o] = w1v;
      wbT[c * 64 + o] = w2v - w1v;
    }
  }
  {
    int nl = t & 63, cw4 = t >> 6;
#pragma unroll
    for (int k = 0; k < 16; ++k) {
      int c = cw4 + 4 * k;
      P[nl * 65 + c] = x[((size_t)b * C_ + c) * N_ + n0 + nl];
    }
  }
  __syncthreads();
  int n = t & 63, og = t >> 6;
  v2f accY[8], accZ[8];
  const v2f zero2 = {0.f, 0.f};
#pragma unroll
  for (int i = 0; i < 8; ++i) { accY[i] = zero2; accZ[i] = zero2; }
  for (int c = 0; c < C_; ++c) {
    float p = P[n * 65 + c];
    v2f pp = {p, p};
    const v2f* wa2 = (const v2f*)&waT[c * 64 + og * 16];
    const v2f* wb2 = (const v2f*)&wbT[c * 64 + og * 16];
#pragma unroll
    for (int i = 0; i < 8; ++i) {
      accY[i] = __builtin_elementwise_fma(pp, wa2[i], accY[i]);
      accZ[i] = __builtin_elementwise_fma(pp, wb2[i], accZ[i]);
    }
  }
  __syncthreads();   // P/waT/wbT dead; overlay YT/ZT
#pragma unroll
  for (int i = 0; i < 8; ++i) {
    YT[n * 65 + og * 16 + 2 * i + 0] = accY[i][0];
    YT[n * 65 + og * 16 + 2 * i + 1] = accY[i][1];
    ZT[n * 65 + og * 16 + 2 * i + 0] = accZ[i][0];
    ZT[n * 65 + og * 16 + 2 * i + 1] = accZ[i][1];
  }
  __syncthreads();
  {
    int nr = t >> 2, o0 = (t & 3) * 16;
    size_t gbase = ((size_t)b * N_ + n0 + nr) * O_ + o0;
#pragma unroll
    for (int j = 0; j < 16; j += 4) {
      float4 yv, zv;
      yv.x = YT[nr * 65 + o0 + j + 0]; yv.y = YT[nr * 65 + o0 + j + 1];
      yv.z = YT[nr * 65 + o0 + j + 2]; yv.w = YT[nr * 65 + o0 + j + 3];
      zv.x = ZT[nr * 65 + o0 + j + 0]; zv.y = ZT[nr * 65 + o0 + j + 1];
      zv.z = ZT[nr * 65 + o0 + j + 2]; zv.w = ZT[nr * 65 + o0 + j + 3];
      *(float4*)&ws[WS_Y + gbase + j] = yv;
      *(float4*)&ws[WS_Z + gbase + j] = zv;
    }
  }
}
#define K1B_LDS 49408

// ===================== k2: barrier-free i8-MFMA KNN + batched selection =====
// Main loop: register-streamed frags (no barriers); selection via LDS pending
// buffer + wave-voted batched flush (amortizes the 20-deep insert chain).
// LDS (45 KB -> 3 blocks/CU):
//   main:  pendk @0 (8192) | pendi @8192 (8192)          [per-thread slices]
//   epi:   list2 @0 (40960, overlays pend after sync) | fidx @40960 (5120)
//          Mt @0 (17664, overlays list2 after merge)
#define K2_LDS 46080

struct FragT {
  i32x4 a00, a01, a10, a11, a20, a21;   // [plane][kk]
  float4 s0, s1, s2, s3;
};

__global__ __launch_bounds__(256, 3) void k2_knn(float* __restrict__ ws)
{
  extern __shared__ char lds_raw[];
  float*  pendk = (float*)lds_raw;
  int*    pendi = (int*)(lds_raw + 8192);
  float2* list2 = (float2*)lds_raw;
  int*    fidx  = (int*)(lds_raw + 40960);
  float*  Mt    = (float*)lds_raw;

  const int t = threadIdx.x;
  const int bid = blockIdx.x;
  const int b = bid & 7;                 // XCD-local batch (id%8 -> XCD)
  const int n0 = (bid >> 3) * 64;
  const int w = t >> 6, l = t & 63, lo5 = l & 31, hi = l >> 5;
  const int qloc = (w & 1) * 32 + lo5;
  const int qg = n0 + qloc;
  const int mhalf = (w >> 1) * 32;
  const int rowm = mhalf + lo5;

  const char* __restrict__ i8b = (const char*)ws + WS_I8B + (size_t)b * 64 * 16384;
  const float* __restrict__ sqg = ws + WS_SQ + (size_t)b * N_;

  // ---- Q fragments straight from global (loop-invariant)
  i32x4 Bq00, Bq01, Bq10, Bq11, Bq20, Bq21;
  {
    const char* qb = i8b + (size_t)(n0 >> 6) * 16384 + qloc * 80 + hi * 16;
    Bq00 = *(const i32x4*)(qb + 0);      Bq01 = *(const i32x4*)(qb + 32);
    Bq10 = *(const i32x4*)(qb + 5120);   Bq11 = *(const i32x4*)(qb + 5152);
    Bq20 = *(const i32x4*)(qb + 10240);  Bq21 = *(const i32x4*)(qb + 10272);
  }

  // ---- selection state: sorted top-20 + pending buffer
  float kd[K_]; int ki[K_];
#pragma unroll
  for (int i = 0; i < K_; ++i) { kd[i] = __builtin_inff(); ki[i] = 0; }
  float kd19 = __builtin_inff();
  int cnt = 0;

  auto flush = [&]() {
#pragma unroll 1
    for (int s = 0; s < 8; ++s) {
      if (__all(s >= cnt)) break;
      if (s < cnt) {
        float kx = pendk[s * 256 + t];
        int mx = pendi[s * 256 + t];
        if (kx < kd[K_ - 1]) {
          bool cc[K_];
#pragma unroll
          for (int i = 0; i < K_; ++i) cc[i] = kx < kd[i];
#pragma unroll
          for (int i = K_ - 1; i >= 1; --i) {
            kd[i] = cc[i-1] ? kd[i-1] : (cc[i] ? kx : kd[i]);
            ki[i] = cc[i-1] ? ki[i-1] : (cc[i] ? mx : ki[i]);
          }
          kd[0] = cc[0] ? kx : kd[0];
          ki[0] = cc[0] ? mx : ki[0];
        }
      }
    }
    cnt = 0;
    kd19 = kd[K_ - 1];
  };

  auto LOADF = [&](FragT& F, int tile) {
    const char* bb = i8b + (size_t)tile * 16384 + rowm * 80 + hi * 16;
    F.a00 = *(const i32x4*)(bb + 0);      F.a01 = *(const i32x4*)(bb + 32);
    F.a10 = *(const i32x4*)(bb + 5120);   F.a11 = *(const i32x4*)(bb + 5152);
    F.a20 = *(const i32x4*)(bb + 10240);  F.a21 = *(const i32x4*)(bb + 10272);
    const float* sp = sqg + tile * 64 + mhalf + 4 * hi;
    F.s0 = *(const float4*)(sp + 0);  F.s1 = *(const float4*)(sp + 8);
    F.s2 = *(const float4*)(sp + 16); F.s3 = *(const float4*)(sp + 24);
  };

  auto BODY = [&](const FragT& F, int step) {
    i32x16 accA = {0,0,0,0,0,0,0,0,0,0,0,0,0,0,0,0};
    i32x16 accB = {0,0,0,0,0,0,0,0,0,0,0,0,0,0,0,0};
    i32x16 accC = {0,0,0,0,0,0,0,0,0,0,0,0,0,0,0,0};
    i32x16 accD = {0,0,0,0,0,0,0,0,0,0,0,0,0,0,0,0};
    accA = __builtin_amdgcn_mfma_i32_32x32x32_i8(F.a20, Bq20, accA, 0, 0, 0);
    accB = __builtin_amdgcn_mfma_i32_32x32x32_i8(F.a20, Bq10, accB, 0, 0, 0);
    accC = __builtin_amdgcn_mfma_i32_32x32x32_i8(F.a10, Bq10, accC, 0, 0, 0);
    accD = __builtin_amdgcn_mfma_i32_32x32x32_i8(F.a10, Bq00, accD, 0, 0, 0);
    accA = __builtin_amdgcn_mfma_i32_32x32x32_i8(F.a21, Bq21, accA, 0, 0, 0);
    accB = __builtin_amdgcn_mfma_i32_32x32x32_i8(F.a10, Bq20, accB, 0, 0, 0);
    accC = __builtin_amdgcn_mfma_i32_32x32x32_i8(F.a20, Bq00, accC, 0, 0, 0);
    accD = __builtin_amdgcn_mfma_i32_32x32x32_i8(F.a00, Bq10, accD, 0, 0, 0);
    accB = __builtin_amdgcn_mfma_i32_32x32x32_i8(F.a21, Bq11, accB, 0, 0, 0);
    accC = __builtin_amdgcn_mfma_i32_32x32x32_i8(F.a00, Bq20, accC, 0, 0, 0);
    accD = __builtin_amdgcn_mfma_i32_32x32x32_i8(F.a11, Bq01, accD, 0, 0, 0);
    accB = __builtin_amdgcn_mfma_i32_32x32x32_i8(F.a11, Bq21, accB, 0, 0, 0);
    accC = __builtin_amdgcn_mfma_i32_32x32x32_i8(F.a11, Bq11, accC, 0, 0, 0);
    accD = __builtin_amdgcn_mfma_i32_32x32x32_i8(F.a01, Bq11, accD, 0, 0, 0);
    accC = __builtin_amdgcn_mfma_i32_32x32x32_i8(F.a21, Bq01, accC, 0, 0, 0);
    accC = __builtin_amdgcn_mfma_i32_32x32x32_i8(F.a01, Bq21, accC, 0, 0, 0);

    float sqa[16] = { F.s0.x,F.s0.y,F.s0.z,F.s0.w, F.s1.x,F.s1.y,F.s1.z,F.s1.w,
                      F.s2.x,F.s2.y,F.s2.z,F.s2.w, F.s3.x,F.s3.y,F.s3.z,F.s3.w };
    const int mbase = step * 64 + mhalf + 4 * hi;
#pragma unroll
    for (int r = 0; r < 16; ++r) {
      float key = fmaf((float)accD[r], -4.656612873077393e-10f,
                  fmaf((float)accC[r], -1.1920928955078125e-7f,
                  fmaf((float)accB[r], -3.0517578125e-5f,
                  fmaf((float)accA[r], -0.0078125f, sqa[r]))));
      int m = mbase + (r & 3) + 8 * (r >> 2);
      if ((key < kd19) & (m != qg)) {
        pendk[cnt * 256 + t] = key;
        pendi[cnt * 256 + t] = m;
        ++cnt;
      }
      if ((r & 3) == 3) { if (__any(cnt >= 4)) flush(); }
    }
  };

  // ---- barrier-free main loop: register ping-pong, 1 tile prefetch ahead
  FragT FA, FB;
  LOADF(FA, 0);
#pragma unroll 1
  for (int s = 0; s < 64; s += 2) {
    LOADF(FB, s + 1);
    BODY(FA, s);
    LOADF(FA, (s + 2 < 64) ? (s + 2) : 63);
    BODY(FB, s + 1);
  }
  flush();
  __syncthreads();   // pend dead; list2 overlays it

  // ---- write per-lane sorted lists: query qloc, list j = (w>>1)*2 + hi
  {
    int j = (w >> 1) * 2 + hi;
#pragma unroll
    for (int s = 0; s < K_; ++s)
      list2[(size_t)(qloc * 4 + j) * K_ + s] = make_float2(kd[s], __int_as_float(ki[s]));
  }
  __syncthreads();
  // ---- 4-way merge -> final 20 indices
  if (t < 64) {
    const float2* la = &list2[(size_t)(t * 4 + 0) * K_];
    const float2* lb = &list2[(size_t)(t * 4 + 1) * K_];
    const float2* lc = &list2[(size_t)(t * 4 + 2) * K_];
    const float2* ld = &list2[(size_t)(t * 4 + 3) * K_];
    int ia = 0, ib2 = 0, ic = 0, id2 = 0;
#pragma unroll 1
    for (int k = 0; k < K_; ++k) {
      float2 fa = la[ia], fb = lb[ib2], fc = lc[ic], fd = ld[id2];
      bool tab = fa.x <= fb.x;
      float2 m1 = tab ? fa : fb;
      bool tcd = fc.x <= fd.x;
      float2 m2 = tcd ? fc : fd;
      bool t12 = m1.x <= m2.x;
      float2 mm = t12 ? m1 : m2;
      fidx[t * K_ + k] = __float_as_int(mm.y);
      ia  += ( tab &  t12) ? 1 : 0;
      ib2 += (!tab &  t12) ? 1 : 0;
      ic  += ( tcd & !t12) ? 1 : 0;
      id2 += (!tcd & !t12) ? 1 : 0;
    }
  }
  __syncthreads();   // list2 dead; Mt overlays it
  // ---- gather-max: M[b][o][n] = max_k Y[b][nbr][o] + Z[b][n][o]
  {
    int q = t & 63;
    int ob = (t >> 6) * 16;
    const float* __restrict__ Yb = ws + WS_Y + (size_t)b * N_ * O_;
    float4 mx[4];
#pragma unroll
    for (int i = 0; i < 4; ++i)
      mx[i] = make_float4(-__builtin_inff(), -__builtin_inff(), -__builtin_inff(), -__builtin_inff());
#pragma unroll 1
    for (int k = 0; k < K_; ++k) {
      int m = fidx[q * K_ + k];
      const float4* yr = (const float4*)&Yb[(size_t)m * O_ + ob];
#pragma unroll
      for (int i = 0; i < 4; ++i) {
        float4 v = yr[i];
        mx[i].x = fmaxf(mx[i].x, v.x);
        mx[i].y = fmaxf(mx[i].y, v.y);
        mx[i].z = fmaxf(mx[i].z, v.z);
        mx[i].w = fmaxf(mx[i].w, v.w);
      }
    }
    const float4* zr = (const float4*)&ws[WS_Z + ((size_t)b * N_ + n0 + q) * O_ + ob];
#pragma unroll
    for (int i = 0; i < 4; ++i) {
      float4 z = zr[i];
      Mt[q * 69 + ob + 4 * i + 0] = mx[i].x + z.x;
      Mt[q * 69 + ob + 4 * i + 1] = mx[i].y + z.y;
      Mt[q * 69 + ob + 4 * i + 2] = mx[i].z + z.z;
      Mt[q * 69 + ob + 4 * i + 3] = mx[i].w + z.w;
    }
  }
  __syncthreads();
  // ---- transpose-write to (B,O,N)
  {
    int o = t >> 2, seg = (t & 3) * 16;
    float* Mrow = ws + WS_M + ((size_t)b * O_ + o) * N_ + n0 + seg;
#pragma unroll
    for (int i = 0; i < 16; i += 4) {
      float4 wv;
      wv.x = Mt[(seg + i + 0) * 69 + o];
      wv.y = Mt[(seg + i + 1) * 69 + o];
      wv.z = Mt[(seg + i + 2) * 69 + o];
      wv.w = Mt[(seg + i + 3) * 69 + o];
      *(float4*)&Mrow[i] = wv;
    }
  }
}

// ===================== k3: per-(b,o) mean/var -> scale/shift =====================
__global__ __launch_bounds__(256) void k3_stats(float* __restrict__ ws)
{
  int bo = blockIdx.x;
  int t = threadIdx.x;
  const float4* Mr = (const float4*)&ws[WS_M + (size_t)bo * N_];
  float s = 0.f, ss = 0.f;
#pragma unroll
  for (int k = 0; k < 4; ++k) {
    float4 v = Mr[t + 256 * k];
    s  += v.x + v.y + v.z + v.w;
    ss += v.x * v.x + v.y * v.y + v.z * v.z + v.w * v.w;
  }
#pragma unroll
  for (int off = 32; off >= 1; off >>= 1) {
    s  += __shfl_down(s, off);
    ss += __shfl_down(ss, off);
  }
  __shared__ float red[8];
  int w = t >> 6;
  if ((t & 63) == 0) { red[w * 2] = s; red[w * 2 + 1] = ss; }
  __syncthreads();
  if (t == 0) {
    float S  = red[0] + red[2] + red[4] + red[6];
    float SS = red[1] + red[3] + red[5] + red[7];
    float mean = S / (float)N_;
    float var = fmaxf(SS / (float)N_ - mean * mean, 0.f);
    float g  = ws[WS_GAMMA + bo];
    float be = ws[WS_BETA + bo];
    float sc = g / sqrtf(var + EPS_);
    ws[WS_SCALE + bo] = sc;
    ws[WS_SHIFT + bo] = be - mean * sc;
  }
}

// ===================== k4: normalize + affine + relu =====================
__global__ __launch_bounds__(256) void k4_apply(const float* __restrict__ ws, float* __restrict__ out)
{
  int i4 = blockIdx.x * 256 + threadIdx.x;
  int bo = i4 >> 10;
  float sc = ws[WS_SCALE + bo], sh = ws[WS_SHIFT + bo];
  float4 v = *(const float4*)&ws[WS_M + (size_t)i4 * 4];
  float4 r;
  r.x = fmaxf(fmaf(v.x, sc, sh), 0.f);
  r.y = fmaxf(fmaf(v.y, sc, sh), 0.f);
  r.z = fmaxf(fmaf(v.z, sc, sh), 0.f);
  r.w = fmaxf(fmaf(v.w, sc, sh), 0.f);
  *(float4*)&out[(size_t)i4 * 4] = r;
}

extern "C" void kernel_launch(void* const* d_in, const int* in_sizes, int n_in,
                              void* d_out, int out_size, void* d_ws, size_t ws_size,
                              hipStream_t stream)
{
  const float* x   = (const float*)d_in[0];
  const float* emb = (const float*)d_in[1];
  const float* cw  = (const float*)d_in[2];
  const float* gw1 = (const float*)d_in[3];
  const float* gb1 = (const float*)d_in[4];
  const float* gw2 = (const float*)d_in[5];
  const float* gb2 = (const float*)d_in[6];
  const float* bw1 = (const float*)d_in[7];
  const float* bb1 = (const float*)d_in[8];
  const float* bw2 = (const float*)d_in[9];
  const float* bb2 = (const float*)d_in[10];
  float* ws  = (float*)d_ws;
  float* out = (float*)d_out;

  k0_mlp<<<1, 256, 0, stream>>>(emb, gw1, gb1, gw2, gb2, bw1, bb1, bw2, bb2, ws);
  k1a_split<<<dim3(64, 8), 256, 0, stream>>>(x, ws);
  k1b_yz<<<dim3(64, 8), 256, K1B_LDS, stream>>>(x, cw, ws);
  k2_knn<<<512, 256, K2_LDS, stream>>>(ws);
  k3_stats<<<512, 256, 0, stream>>>(ws);
  k4_apply<<<2048, 256, 0, stream>>>(ws, out);
}

// Round 10
// 679.967 us; speedup vs baseline: 1.2685x; 1.2685x over previous
//
#include <hip/hip_runtime.h>

#define B_ 8
#define C_ 64
#define N_ 4096
#define O_ 64
#define E_ 128
#define K_ 20
#define EPS_ 1e-5f

typedef float v2f __attribute__((ext_vector_type(2)));
typedef __attribute__((ext_vector_type(4)))  int  i32x4;
typedef __attribute__((ext_vector_type(16))) int  i32x16;
typedef __attribute__((ext_vector_type(16))) char c16;

// ---- workspace layout (float offsets) ----
#define WS_SQ    0                          // (B,N) |p_quant|^2 fp32
#define WS_Y     32768                      // (B,N,O)
#define WS_Z     (WS_Y + B_*N_*O_)          // (B,N,O)
#define WS_M     (WS_Z + B_*N_*O_)          // (B,O,N)
#define WS_GAMMA (WS_M + B_*N_*O_)
#define WS_BETA  (WS_GAMMA + 512)
#define WS_SCALE (WS_BETA + 512)
#define WS_SHIFT (WS_SCALE + 512)
#define WS_END_F (WS_SHIFT + 512)
#define WS_I8B   (WS_END_F * 4)             // BYTE offset of i8 limb blobs
// blob per (b,tile): 16384 B = 3 planes x (64 rows x 80 B) + 1024 pad
// plane p, row r, channel c: byte p*5120 + r*80 + c

// ===================== k0: domain MLPs -> gamma/beta =====================
__global__ __launch_bounds__(256) void k0_mlp(const float* __restrict__ emb,
    const float* __restrict__ gw1, const float* __restrict__ gb1,
    const float* __restrict__ gw2, const float* __restrict__ gb2,
    const float* __restrict__ bw1, const float* __restrict__ bb1,
    const float* __restrict__ bw2, const float* __restrict__ bb2,
    float* __restrict__ ws)
{
  __shared__ float s_emb[B_][E_];
  __shared__ float s_h[2][B_][E_];
  int t = threadIdx.x;
  for (int i = t; i < B_*E_; i += 256) s_emb[i >> 7][i & 127] = emb[i];
  __syncthreads();
  {
    int net = t >> 7, e = t & 127;
    const float* w1 = net ? bw1 : gw1;
    const float* b1 = net ? bb1 : gb1;
    float acc[B_];
#pragma unroll
    for (int b = 0; b < B_; ++b) acc[b] = 0.f;
    const float* row = w1 + e * E_;
    for (int j = 0; j < E_; j += 4) {
      float4 w = *(const float4*)(row + j);
#pragma unroll
      for (int b = 0; b < B_; ++b)
        acc[b] += s_emb[b][j]*w.x + s_emb[b][j+1]*w.y + s_emb[b][j+2]*w.z + s_emb[b][j+3]*w.w;
    }
    float bias = b1[e];
#pragma unroll
    for (int b = 0; b < B_; ++b) s_h[net][b][e] = fmaxf(acc[b] + bias, 0.f);
  }
  __syncthreads();
  for (int r = 0; r < 4; ++r) {
    int idx = t + 256 * r;
    int net = idx >> 9, b = (idx >> 6) & 7, o = idx & 63;
    const float* w2 = net ? bw2 : gw2;
    const float* b2 = net ? bb2 : gb2;
    const float* row = w2 + o * E_;
    float acc = 0.f;
    for (int e = 0; e < E_; e += 4) {
      float4 w = *(const float4*)(row + e);
      acc += s_h[net][b][e]*w.x + s_h[net][b][e+1]*w.y + s_h[net][b][e+2]*w.z + s_h[net][b][e+3]*w.w;
    }
    acc += b2[o];
    if (net == 0) ws[WS_GAMMA + b*O_ + o] = 1.f + acc;
    else          ws[WS_BETA  + b*O_ + o] = acc;
  }
}

// ===================== k1a: quantize x -> 3 i8 limb planes + exact |p|^2 ====
__global__ __launch_bounds__(256) void k1a_split(const float* __restrict__ x, float* __restrict__ ws)
{
  __shared__ double sqp[4][64];
  int b = blockIdx.y, T = blockIdx.x, n0 = T * 64;
  int t = threadIdx.x;
  int r = t & 63, qc = t >> 6;
  char* blob = (char*)ws + WS_I8B + (size_t)(b * 64 + T) * 16384;
  c16 v0, v1, v2;
  double sq = 0.0;
#pragma unroll
  for (int e = 0; e < 16; ++e) {
    int c = qc * 16 + e;
    float v = x[((size_t)(b * 64 + c)) * 4096 + n0 + r];
    int X = __float2int_rn(v * 1048576.0f);          // 2^20
    sq += (double)X * (double)X;
    int L0 = ((X + 128) & 255) - 128;
    int X1 = (X - L0) >> 8;
    int L1 = ((X1 + 128) & 255) - 128;
    int L2 = (X1 - L1) >> 8;
    v0[e] = (char)L0; v1[e] = (char)L1; v2[e] = (char)L2;
  }
  *(c16*)(blob + 0*5120 + r*80 + qc*16) = v0;
  *(c16*)(blob + 1*5120 + r*80 + qc*16) = v1;
  *(c16*)(blob + 2*5120 + r*80 + qc*16) = v2;
  sqp[qc][r] = sq;
  __syncthreads();
  if (t < 64)
    ws[WS_SQ + b * N_ + n0 + t] =
      (float)((sqp[0][t] + sqp[1][t] + sqp[2][t] + sqp[3][t]) * (1.0 / 1099511627776.0)); // 2^-40
}

// ===================== k1b: Y = wa.p, Z = wb.p (coalesced writes) ===========
__global__ __launch_bounds__(256) void k1b_yz(const float* __restrict__ x,
                                              const float* __restrict__ cw_, float* __restrict__ ws)
{
  extern __shared__ char l1b[];
  float* P   = (float*)l1b;              // [64][65]
  float* waT = (float*)(l1b + 16640);    // [64][64]
  float* wbT = (float*)(l1b + 33024);    // [64][64]
  float* YT  = (float*)l1b;              // [64][65] overlay
  float* ZT  = (float*)(l1b + 16900);    // [64][65] overlay
  int b = blockIdx.y, n0 = blockIdx.x * 64;
  int t = threadIdx.x;
  {
    int o = t & 63, cb = t >> 6;
#pragma unroll
    for (int k = 0; k < 16; ++k) {
      int c = cb + 4 * k;
      float w1v = cw_[o * 128 + c];
      float w2v = cw_[o * 128 + 64 + c];
      waT[c * 64 + o] = w1v;
      wbT[c * 64 + o] = w2v - w1v;
    }
  }
  {
    int nl = t & 63, cw4 = t >> 6;
#pragma unroll
    for (int k = 0; k < 16; ++k) {
      int c = cw4 + 4 * k;
      P[nl * 65 + c] = x[((size_t)b * C_ + c) * N_ + n0 + nl];
    }
  }
  __syncthreads();
  int n = t & 63, og = t >> 6;
  v2f accY[8], accZ[8];
  const v2f zero2 = {0.f, 0.f};
#pragma unroll
  for (int i = 0; i < 8; ++i) { accY[i] = zero2; accZ[i] = zero2; }
  for (int c = 0; c < C_; ++c) {
    float p = P[n * 65 + c];
    v2f pp = {p, p};
    const v2f* wa2 = (const v2f*)&waT[c * 64 + og * 16];
    const v2f* wb2 = (const v2f*)&wbT[c * 64 + og * 16];
#pragma unroll
    for (int i = 0; i < 8; ++i) {
      accY[i] = __builtin_elementwise_fma(pp, wa2[i], accY[i]);
      accZ[i] = __builtin_elementwise_fma(pp, wb2[i], accZ[i]);
    }
  }
  __syncthreads();   // P/waT/wbT dead; overlay YT/ZT
#pragma unroll
  for (int i = 0; i < 8; ++i) {
    YT[n * 65 + og * 16 + 2 * i + 0] = accY[i][0];
    YT[n * 65 + og * 16 + 2 * i + 1] = accY[i][1];
    ZT[n * 65 + og * 16 + 2 * i + 0] = accZ[i][0];
    ZT[n * 65 + og * 16 + 2 * i + 1] = accZ[i][1];
  }
  __syncthreads();
  {
    int nr = t >> 2, o0 = (t & 3) * 16;
    size_t gbase = ((size_t)b * N_ + n0 + nr) * O_ + o0;
#pragma unroll
    for (int j = 0; j < 16; j += 4) {
      float4 yv, zv;
      yv.x = YT[nr * 65 + o0 + j + 0]; yv.y = YT[nr * 65 + o0 + j + 1];
      yv.z = YT[nr * 65 + o0 + j + 2]; yv.w = YT[nr * 65 + o0 + j + 3];
      zv.x = ZT[nr * 65 + o0 + j + 0]; zv.y = ZT[nr * 65 + o0 + j + 1];
      zv.z = ZT[nr * 65 + o0 + j + 2]; zv.w = ZT[nr * 65 + o0 + j + 3];
      *(float4*)&ws[WS_Y + gbase + j] = yv;
      *(float4*)&ws[WS_Z + gbase + j] = zv;
    }
  }
}
#define K1B_LDS 49408

// ===================== k2: barrier-free i8-MFMA KNN + batched selection =====
// Main loop: register-streamed frags (no barriers); selection via LDS pending
// buffer + wave-voted batched flush (amortizes the 20-deep insert chain).
// NOTE R9 lesson: __launch_bounds__(256,3) capped VGPR at 84 -> accumulator
// spill -> 625 MB scratch writes. Use (256,2): full 256-VGPR budget, no spill;
// occupancy is then best-effort (LDS 45 KB still admits 3 blocks/CU if the
// allocator lands <=170 VGPR).
// LDS (45 KB):
//   main:  pendk @0 (8192) | pendi @8192 (8192)          [per-thread slices]
//   epi:   list2 @0 (40960, overlays pend after sync) | fidx @40960 (5120)
//          Mt @0 (17664, overlays list2 after merge)
#define K2_LDS 46080

struct FragT {
  i32x4 a00, a01, a10, a11, a20, a21;   // [plane][kk]
  float4 s0, s1, s2, s3;
};

__global__ __launch_bounds__(256, 2) void k2_knn(float* __restrict__ ws)
{
  extern __shared__ char lds_raw[];
  float*  pendk = (float*)lds_raw;
  int*    pendi = (int*)(lds_raw + 8192);
  float2* list2 = (float2*)lds_raw;
  int*    fidx  = (int*)(lds_raw + 40960);
  float*  Mt    = (float*)lds_raw;

  const int t = threadIdx.x;
  const int bid = blockIdx.x;
  const int b = bid & 7;                 // XCD-local batch (id%8 -> XCD)
  const int n0 = (bid >> 3) * 64;
  const int w = t >> 6, l = t & 63, lo5 = l & 31, hi = l >> 5;
  const int qloc = (w & 1) * 32 + lo5;
  const int qg = n0 + qloc;
  const int mhalf = (w >> 1) * 32;
  const int rowm = mhalf + lo5;

  const char* __restrict__ i8b = (const char*)ws + WS_I8B + (size_t)b * 64 * 16384;
  const float* __restrict__ sqg = ws + WS_SQ + (size_t)b * N_;

  // ---- Q fragments straight from global (loop-invariant)
  i32x4 Bq00, Bq01, Bq10, Bq11, Bq20, Bq21;
  {
    const char* qb = i8b + (size_t)(n0 >> 6) * 16384 + qloc * 80 + hi * 16;
    Bq00 = *(const i32x4*)(qb + 0);      Bq01 = *(const i32x4*)(qb + 32);
    Bq10 = *(const i32x4*)(qb + 5120);   Bq11 = *(const i32x4*)(qb + 5152);
    Bq20 = *(const i32x4*)(qb + 10240);  Bq21 = *(const i32x4*)(qb + 10272);
  }

  // ---- selection state: sorted top-20 + pending buffer
  float kd[K_]; int ki[K_];
#pragma unroll
  for (int i = 0; i < K_; ++i) { kd[i] = __builtin_inff(); ki[i] = 0; }
  float kd19 = __builtin_inff();
  int cnt = 0;

  auto flush = [&]() {
#pragma unroll 1
    for (int s = 0; s < 8; ++s) {
      if (__all(s >= cnt)) break;
      if (s < cnt) {
        float kx = pendk[s * 256 + t];
        int mx = pendi[s * 256 + t];
        if (kx < kd[K_ - 1]) {
          bool cc[K_];
#pragma unroll
          for (int i = 0; i < K_; ++i) cc[i] = kx < kd[i];
#pragma unroll
          for (int i = K_ - 1; i >= 1; --i) {
            kd[i] = cc[i-1] ? kd[i-1] : (cc[i] ? kx : kd[i]);
            ki[i] = cc[i-1] ? ki[i-1] : (cc[i] ? mx : ki[i]);
          }
          kd[0] = cc[0] ? kx : kd[0];
          ki[0] = cc[0] ? mx : ki[0];
        }
      }
    }
    cnt = 0;
    kd19 = kd[K_ - 1];
  };

  auto LOADF = [&](FragT& F, int tile) {
    const char* bb = i8b + (size_t)tile * 16384 + rowm * 80 + hi * 16;
    F.a00 = *(const i32x4*)(bb + 0);      F.a01 = *(const i32x4*)(bb + 32);
    F.a10 = *(const i32x4*)(bb + 5120);   F.a11 = *(const i32x4*)(bb + 5152);
    F.a20 = *(const i32x4*)(bb + 10240);  F.a21 = *(const i32x4*)(bb + 10272);
    const float* sp = sqg + tile * 64 + mhalf + 4 * hi;
    F.s0 = *(const float4*)(sp + 0);  F.s1 = *(const float4*)(sp + 8);
    F.s2 = *(const float4*)(sp + 16); F.s3 = *(const float4*)(sp + 24);
  };

  auto BODY = [&](const FragT& F, int step) {
    i32x16 accA = {0,0,0,0,0,0,0,0,0,0,0,0,0,0,0,0};
    i32x16 accB = {0,0,0,0,0,0,0,0,0,0,0,0,0,0,0,0};
    i32x16 accC = {0,0,0,0,0,0,0,0,0,0,0,0,0,0,0,0};
    i32x16 accD = {0,0,0,0,0,0,0,0,0,0,0,0,0,0,0,0};
    accA = __builtin_amdgcn_mfma_i32_32x32x32_i8(F.a20, Bq20, accA, 0, 0, 0);
    accB = __builtin_amdgcn_mfma_i32_32x32x32_i8(F.a20, Bq10, accB, 0, 0, 0);
    accC = __builtin_amdgcn_mfma_i32_32x32x32_i8(F.a10, Bq10, accC, 0, 0, 0);
    accD = __builtin_amdgcn_mfma_i32_32x32x32_i8(F.a10, Bq00, accD, 0, 0, 0);
    accA = __builtin_amdgcn_mfma_i32_32x32x32_i8(F.a21, Bq21, accA, 0, 0, 0);
    accB = __builtin_amdgcn_mfma_i32_32x32x32_i8(F.a10, Bq20, accB, 0, 0, 0);
    accC = __builtin_amdgcn_mfma_i32_32x32x32_i8(F.a20, Bq00, accC, 0, 0, 0);
    accD = __builtin_amdgcn_mfma_i32_32x32x32_i8(F.a00, Bq10, accD, 0, 0, 0);
    accB = __builtin_amdgcn_mfma_i32_32x32x32_i8(F.a21, Bq11, accB, 0, 0, 0);
    accC = __builtin_amdgcn_mfma_i32_32x32x32_i8(F.a00, Bq20, accC, 0, 0, 0);
    accD = __builtin_amdgcn_mfma_i32_32x32x32_i8(F.a11, Bq01, accD, 0, 0, 0);
    accB = __builtin_amdgcn_mfma_i32_32x32x32_i8(F.a11, Bq21, accB, 0, 0, 0);
    accC = __builtin_amdgcn_mfma_i32_32x32x32_i8(F.a11, Bq11, accC, 0, 0, 0);
    accD = __builtin_amdgcn_mfma_i32_32x32x32_i8(F.a01, Bq11, accD, 0, 0, 0);
    accC = __builtin_amdgcn_mfma_i32_32x32x32_i8(F.a21, Bq01, accC, 0, 0, 0);
    accC = __builtin_amdgcn_mfma_i32_32x32x32_i8(F.a01, Bq21, accC, 0, 0, 0);

    float sqa[16] = { F.s0.x,F.s0.y,F.s0.z,F.s0.w, F.s1.x,F.s1.y,F.s1.z,F.s1.w,
                      F.s2.x,F.s2.y,F.s2.z,F.s2.w, F.s3.x,F.s3.y,F.s3.z,F.s3.w };
    const int mbase = step * 64 + mhalf + 4 * hi;
#pragma unroll
    for (int r = 0; r < 16; ++r) {
      float key = fmaf((float)accD[r], -4.656612873077393e-10f,
                  fmaf((float)accC[r], -1.1920928955078125e-7f,
                  fmaf((float)accB[r], -3.0517578125e-5f,
                  fmaf((float)accA[r], -0.0078125f, sqa[r]))));
      int m = mbase + (r & 3) + 8 * (r >> 2);
      if ((key < kd19) & (m != qg)) {
        pendk[cnt * 256 + t] = key;
        pendi[cnt * 256 + t] = m;
        ++cnt;
      }
      if ((r & 3) == 3) { if (__any(cnt >= 4)) flush(); }
    }
  };

  // ---- barrier-free main loop: register ping-pong, 1 tile prefetch ahead
  FragT FA, FB;
  LOADF(FA, 0);
#pragma unroll 1
  for (int s = 0; s < 64; s += 2) {
    LOADF(FB, s + 1);
    BODY(FA, s);
    LOADF(FA, (s + 2 < 64) ? (s + 2) : 63);
    BODY(FB, s + 1);
  }
  flush();
  __syncthreads();   // pend dead; list2 overlays it

  // ---- write per-lane sorted lists: query qloc, list j = (w>>1)*2 + hi
  {
    int j = (w >> 1) * 2 + hi;
#pragma unroll
    for (int s = 0; s < K_; ++s)
      list2[(size_t)(qloc * 4 + j) * K_ + s] = make_float2(kd[s], __int_as_float(ki[s]));
  }
  __syncthreads();
  // ---- 4-way merge -> final 20 indices
  if (t < 64) {
    const float2* la = &list2[(size_t)(t * 4 + 0) * K_];
    const float2* lb = &list2[(size_t)(t * 4 + 1) * K_];
    const float2* lc = &list2[(size_t)(t * 4 + 2) * K_];
    const float2* ld = &list2[(size_t)(t * 4 + 3) * K_];
    int ia = 0, ib2 = 0, ic = 0, id2 = 0;
#pragma unroll 1
    for (int k = 0; k < K_; ++k) {
      float2 fa = la[ia], fb = lb[ib2], fc = lc[ic], fd = ld[id2];
      bool tab = fa.x <= fb.x;
      float2 m1 = tab ? fa : fb;
      bool tcd = fc.x <= fd.x;
      float2 m2 = tcd ? fc : fd;
      bool t12 = m1.x <= m2.x;
      float2 mm = t12 ? m1 : m2;
      fidx[t * K_ + k] = __float_as_int(mm.y);
      ia  += ( tab &  t12) ? 1 : 0;
      ib2 += (!tab &  t12) ? 1 : 0;
      ic  += ( tcd & !t12) ? 1 : 0;
      id2 += (!tcd & !t12) ? 1 : 0;
    }
  }
  __syncthreads();   // list2 dead; Mt overlays it
  // ---- gather-max: M[b][o][n] = max_k Y[b][nbr][o] + Z[b][n][o]
  {
    int q = t & 63;
    int ob = (t >> 6) * 16;
    const float* __restrict__ Yb = ws + WS_Y + (size_t)b * N_ * O_;
    float4 mx[4];
#pragma unroll
    for (int i = 0; i < 4; ++i)
      mx[i] = make_float4(-__builtin_inff(), -__builtin_inff(), -__builtin_inff(), -__builtin_inff());
#pragma unroll 1
    for (int k = 0; k < K_; ++k) {
      int m = fidx[q * K_ + k];
      const float4* yr = (const float4*)&Yb[(size_t)m * O_ + ob];
#pragma unroll
      for (int i = 0; i < 4; ++i) {
        float4 v = yr[i];
        mx[i].x = fmaxf(mx[i].x, v.x);
        mx[i].y = fmaxf(mx[i].y, v.y);
        mx[i].z = fmaxf(mx[i].z, v.z);
        mx[i].w = fmaxf(mx[i].w, v.w);
      }
    }
    const float4* zr = (const float4*)&ws[WS_Z + ((size_t)b * N_ + n0 + q) * O_ + ob];
#pragma unroll
    for (int i = 0; i < 4; ++i) {
      float4 z = zr[i];
      Mt[q * 69 + ob + 4 * i + 0] = mx[i].x + z.x;
      Mt[q * 69 + ob + 4 * i + 1] = mx[i].y + z.y;
      Mt[q * 69 + ob + 4 * i + 2] = mx[i].z + z.z;
      Mt[q * 69 + ob + 4 * i + 3] = mx[i].w + z.w;
    }
  }
  __syncthreads();
  // ---- transpose-write to (B,O,N)
  {
    int o = t >> 2, seg = (t & 3) * 16;
    float* Mrow = ws + WS_M + ((size_t)b * O_ + o) * N_ + n0 + seg;
#pragma unroll
    for (int i = 0; i < 16; i += 4) {
      float4 wv;
      wv.x = Mt[(seg + i + 0) * 69 + o];
      wv.y = Mt[(seg + i + 1) * 69 + o];
      wv.z = Mt[(seg + i + 2) * 69 + o];
      wv.w = Mt[(seg + i + 3) * 69 + o];
      *(float4*)&Mrow[i] = wv;
    }
  }
}

// ===================== k3: per-(b,o) mean/var -> scale/shift =====================
__global__ __launch_bounds__(256) void k3_stats(float* __restrict__ ws)
{
  int bo = blockIdx.x;
  int t = threadIdx.x;
  const float4* Mr = (const float4*)&ws[WS_M + (size_t)bo * N_];
  float s = 0.f, ss = 0.f;
#pragma unroll
  for (int k = 0; k < 4; ++k) {
    float4 v = Mr[t + 256 * k];
    s  += v.x + v.y + v.z + v.w;
    ss += v.x * v.x + v.y * v.y + v.z * v.z + v.w * v.w;
  }
#pragma unroll
  for (int off = 32; off >= 1; off >>= 1) {
    s  += __shfl_down(s, off);
    ss += __shfl_down(ss, off);
  }
  __shared__ float red[8];
  int w = t >> 6;
  if ((t & 63) == 0) { red[w * 2] = s; red[w * 2 + 1] = ss; }
  __syncthreads();
  if (t == 0) {
    float S  = red[0] + red[2] + red[4] + red[6];
    float SS = red[1] + red[3] + red[5] + red[7];
    float mean = S / (float)N_;
    float var = fmaxf(SS / (float)N_ - mean * mean, 0.f);
    float g  = ws[WS_GAMMA + bo];
    float be = ws[WS_BETA + bo];
    float sc = g / sqrtf(var + EPS_);
    ws[WS_SCALE + bo] = sc;
    ws[WS_SHIFT + bo] = be - mean * sc;
  }
}

// ===================== k4: normalize + affine + relu =====================
__global__ __launch_bounds__(256) void k4_apply(const float* __restrict__ ws, float* __restrict__ out)
{
  int i4 = blockIdx.x * 256 + threadIdx.x;
  int bo = i4 >> 10;
  float sc = ws[WS_SCALE + bo], sh = ws[WS_SHIFT + bo];
  float4 v = *(const float4*)&ws[WS_M + (size_t)i4 * 4];
  float4 r;
  r.x = fmaxf(fmaf(v.x, sc, sh), 0.f);
  r.y = fmaxf(fmaf(v.y, sc, sh), 0.f);
  r.z = fmaxf(fmaf(v.z, sc, sh), 0.f);
  r.w = fmaxf(fmaf(v.w, sc, sh), 0.f);
  *(float4*)&out[(size_t)i4 * 4] = r;
}

extern "C" void kernel_launch(void* const* d_in, const int* in_sizes, int n_in,
                              void* d_out, int out_size, void* d_ws, size_t ws_size,
                              hipStream_t stream)
{
  const float* x   = (const float*)d_in[0];
  const float* emb = (const float*)d_in[1];
  const float* cw  = (const float*)d_in[2];
  const float* gw1 = (const float*)d_in[3];
  const float* gb1 = (const float*)d_in[4];
  const float* gw2 = (const float*)d_in[5];
  const float* gb2 = (const float*)d_in[6];
  const float* bw1 = (const float*)d_in[7];
  const float* bb1 = (const float*)d_in[8];
  const float* bw2 = (const float*)d_in[9];
  const float* bb2 = (const float*)d_in[10];
  float* ws  = (float*)d_ws;
  float* out = (float*)d_out;

  k0_mlp<<<1, 256, 0, stream>>>(emb, gw1, gb1, gw2, gb2, bw1, bb1, bw2, bb2, ws);
  k1a_split<<<dim3(64, 8), 256, 0, stream>>>(x, ws);
  k1b_yz<<<dim3(64, 8), 256, K1B_LDS, stream>>>(x, cw, ws);
  k2_knn<<<512, 256, K2_LDS, stream>>>(ws);
  k3_stats<<<512, 256, 0, stream>>>(ws);
  k4_apply<<<2048, 256, 0, stream>>>(ws, out);
}